// Round 10
// baseline (899.493 us; speedup 1.0000x reference)
//
#include <hip/hip_runtime.h>
#include <math.h>

#define N_NODES 100000
#define N_EDGES 1000000
#define IN_F 128
#define HID 64
#define OUT_F 64
#define NLAYERS 4
#define ALPHA 0.1f
#define BN_EPS 1e-5f

#define SCAN_BLK 256
#define NSCAN_BLOCKS ((N_NODES + SCAN_BLK - 1) / SCAN_BLK)   // 391
#define NBUCK ((N_NODES + 127) >> 7)                         // 782 row-range buckets

// ---- workspace layout (bytes) ----
static const size_t OFF_X0       = 0;                       // N*64*4 = 25600000
static const size_t OFF_HA       = 25600000;                // also: edge-partition temp (8MB, dead before spmm)
static const size_t OFF_HB       = 51200000;
static const size_t OFF_GB       = 76800000;                // N*64*2 = 12800000 (bf16, dinv-prescaled)
static const size_t OFF_SORTED   = 89600000;                // E*4 = 4000000
static const size_t OFF_CNT      = 93600000;                // N*4 ; reused as bucket cursors after scan
static const size_t OFF_STATS    = 94000000;                // 512*4 = 2048
static const size_t OFF_DINV     = 94002048;                // N*4
static const size_t OFF_ROWSTART = 94402048;                // (N+1)*4 -> 400016
static const size_t OFF_CURSOR   = 94802064;                // N*4
static const size_t OFF_BSUM     = 95202064;                // 391*4 -> pad 2048; end = 95204112
static const size_t ZERO_OFF     = OFF_CNT;
static const size_t ZERO_BYTES   = 402048;

__device__ __forceinline__ unsigned short f2b(float f) {
    unsigned int u = __float_as_uint(f);
    u += 0x7FFFu + ((u >> 16) & 1u);        // round-to-nearest-even
    return (unsigned short)(u >> 16);
}
__device__ __forceinline__ float b2f(unsigned short h) {
    return __uint_as_float(((unsigned int)h) << 16);
}

__global__ void hist_kernel(const int* __restrict__ row, int* __restrict__ cnt, int e) {
    int i = blockIdx.x * blockDim.x + threadIdx.x;
    if (i < e) atomicAdd(&cnt[row[i]], 1);
}

__global__ void dinv_kernel(const int* __restrict__ cnt, float* __restrict__ dinv, int n) {
    int i = blockIdx.x * blockDim.x + threadIdx.x;
    if (i < n) {
        int d = cnt[i];
        dinv[i] = d > 0 ? rsqrtf((float)d) : 0.0f;
    }
}

// ---- 3-phase multi-block exclusive scan of cnt -> rs[0..n], cur ----
__global__ __launch_bounds__(SCAN_BLK) void blocksum_kernel(const int* __restrict__ cnt,
        int* __restrict__ bsum, int n) {
    __shared__ int red[SCAN_BLK / 64];
    int i = blockIdx.x * SCAN_BLK + threadIdx.x;
    int v = (i < n) ? cnt[i] : 0;
#pragma unroll
    for (int off = 32; off > 0; off >>= 1) v += __shfl_down(v, off, 64);
    if ((threadIdx.x & 63) == 0) red[threadIdx.x >> 6] = v;
    __syncthreads();
    if (threadIdx.x == 0) {
        int s = 0;
#pragma unroll
        for (int j = 0; j < SCAN_BLK / 64; ++j) s += red[j];
        bsum[blockIdx.x] = s;
    }
}

__global__ __launch_bounds__(512) void scan_bsum_kernel(int* __restrict__ bsum, int nb) {
    __shared__ int lds[512];
    int t = threadIdx.x;
    lds[t] = (t < nb) ? bsum[t] : 0;
    __syncthreads();
    for (int off = 1; off < 512; off <<= 1) {
        int v = lds[t];
        int add = (t >= off) ? lds[t - off] : 0;
        __syncthreads();
        lds[t] = v + add;
        __syncthreads();
    }
    if (t < nb) bsum[t] = (t == 0) ? 0 : lds[t - 1];
}

__global__ __launch_bounds__(SCAN_BLK) void scan_write_kernel(const int* __restrict__ cnt,
        const int* __restrict__ bsum, int* __restrict__ rs, int* __restrict__ cur, int n) {
    __shared__ int lds[SCAN_BLK];
    int t = threadIdx.x;
    int i = blockIdx.x * SCAN_BLK + t;
    int c = (i < n) ? cnt[i] : 0;
    lds[t] = c;
    __syncthreads();
    for (int off = 1; off < SCAN_BLK; off <<= 1) {
        int v = lds[t];
        int add = (t >= off) ? lds[t - off] : 0;
        __syncthreads();
        lds[t] = v + add;
        __syncthreads();
    }
    if (i < n) {
        int excl = bsum[blockIdx.x] + lds[t] - c;
        rs[i] = excl;
        cur[i] = excl;
        if (i == n - 1) rs[n] = excl + c;
    }
}

// bucket cursors = CSR offset of each 128-row bucket (reuses cnt storage)
__global__ void bcur_init_kernel(const int* __restrict__ rs, int* __restrict__ bcur, int nb) {
    int b = blockIdx.x * blockDim.x + threadIdx.x;
    if (b < nb) bcur[b] = rs[b << 7];
}

// pass 1: partition edges into row-range buckets (writes semi-sequential per bucket)
__global__ void partition_kernel(const int* __restrict__ edges, int* __restrict__ bcur,
                                 int2* __restrict__ temp, int e) {
    int i = blockIdx.x * blockDim.x + threadIdx.x;
    if (i < e) {
        int r = edges[i];
        int c = edges[e + i];
        int pos = atomicAdd(&bcur[r >> 7], 1);
        temp[pos] = make_int2(r, c);
    }
}

// pass 2: exact CSR scatter; writes land in ~5KB L2-resident windows (low write-amp)
__global__ void scatter2_kernel(const int2* __restrict__ temp, int* __restrict__ cur,
                                int* __restrict__ scol, int e) {
    int i = blockIdx.x * blockDim.x + threadIdx.x;
    if (i < e) {
        int2 rc = temp[i];
        int pos = atomicAdd(&cur[rc.x], 1);
        scol[pos] = rc.y;
    }
}

// fc0 as classic LDS-tiled fp32 GEMM: [N,128]@[128,64] + bias, relu, bf16 twin.
__global__ __launch_bounds__(256, 4) void fc0_kernel(const float* __restrict__ x,
        const float* __restrict__ W0, const float* __restrict__ b0,
        const float* __restrict__ dinv, float* __restrict__ out,
        unsigned short* __restrict__ g, int n) {
    __shared__ float At[64][68];   // x^T slice: At[k][r]
    __shared__ float Bt[64][68];   // W0 slice:  Bt[k][c]
    int t = threadIdx.x;
    int base = blockIdx.x * 64;
    int tx = t & 15, ty = t >> 4;
    int r0 = ty * 4, c0 = tx * 4;
    float acc[4][4] = {{0.f}};
    for (int kc = 0; kc < IN_F; kc += 64) {
        __syncthreads();
#pragma unroll
        for (int i = 0; i < 4; ++i) {           // stage x tile (64 rows x 64 k)
            int idx = (i * 256 + t) * 4;
            int r = idx >> 6, kk = idx & 63;
            int rr = base + r; if (rr >= n) rr = n - 1;
            float4 v = *(const float4*)(x + (size_t)rr * IN_F + kc + kk);
            At[kk][r] = v.x; At[kk + 1][r] = v.y; At[kk + 2][r] = v.z; At[kk + 3][r] = v.w;
        }
#pragma unroll
        for (int i = 0; i < 4; ++i) {           // stage W0 slice (64 k x 64 c)
            int idx = (i * 256 + t) * 4;
            int k = idx >> 6, c = idx & 63;
            float4 v = *(const float4*)(W0 + (size_t)(kc + k) * HID + c);
            Bt[k][c] = v.x; Bt[k][c + 1] = v.y; Bt[k][c + 2] = v.z; Bt[k][c + 3] = v.w;
        }
        __syncthreads();
#pragma unroll 4
        for (int k = 0; k < 64; ++k) {
            float4 a = *(const float4*)&At[k][r0];
            float4 b = *(const float4*)&Bt[k][c0];
            acc[0][0] += a.x * b.x; acc[0][1] += a.x * b.y; acc[0][2] += a.x * b.z; acc[0][3] += a.x * b.w;
            acc[1][0] += a.y * b.x; acc[1][1] += a.y * b.y; acc[1][2] += a.y * b.z; acc[1][3] += a.y * b.w;
            acc[2][0] += a.z * b.x; acc[2][1] += a.z * b.y; acc[2][2] += a.z * b.z; acc[2][3] += a.z * b.w;
            acc[3][0] += a.w * b.x; acc[3][1] += a.w * b.y; acc[3][2] += a.w * b.z; acc[3][3] += a.w * b.w;
        }
    }
    float4 bias = *(const float4*)(b0 + c0);
#pragma unroll
    for (int i = 0; i < 4; ++i) {
        int r = base + r0 + i;
        if (r < n) {
            float v0 = acc[i][0] + bias.x; v0 = v0 > 0.f ? v0 : 0.f;
            float v1 = acc[i][1] + bias.y; v1 = v1 > 0.f ? v1 : 0.f;
            float v2 = acc[i][2] + bias.z; v2 = v2 > 0.f ? v2 : 0.f;
            float v3 = acc[i][3] + bias.w; v3 = v3 > 0.f ? v3 : 0.f;
            *(float4*)(out + (size_t)r * HID + c0) = make_float4(v0, v1, v2, v3);
            float dr = dinv[r];
            ushort4 gu;
            gu.x = f2b(dr * v0); gu.y = f2b(dr * v1);
            gu.z = f2b(dr * v2); gu.w = f2b(dr * v3);
            *(ushort4*)(g + (size_t)r * HID + c0) = gu;
        }
    }
}

// SPMM from bf16 dinv-prescaled gather buffer: one 128B line per edge.
__global__ __launch_bounds__(256, 8) void spmm_kernel(const unsigned short* __restrict__ g,
        const float* __restrict__ x0, const float* __restrict__ dinv,
        const int* __restrict__ rs, const int* __restrict__ scol,
        float* __restrict__ sout, int n) {
    int wave = threadIdx.x >> 6, lane = threadIdx.x & 63;
    int nw = gridDim.x * 4;
    for (int r = blockIdx.x * 4 + wave; r < n; r += nw) {
        int e0 = rs[r], e1 = rs[r + 1];
        float agg = 0.f;
        for (int e = e0; e < e1; e += 8) {
            int cc[8];
            float vv[8];
#pragma unroll
            for (int j = 0; j < 8; ++j) {
                int ee = e + j;
                cc[j] = scol[ee < e1 ? ee : e1 - 1];
            }
#pragma unroll
            for (int j = 0; j < 8; ++j) {
                float v = b2f(g[(size_t)cc[j] * HID + lane]);
                vv[j] = (e + j < e1) ? v : 0.f;
            }
            agg += ((vv[0] + vv[1]) + (vv[2] + vv[3])) +
                   ((vv[4] + vv[5]) + (vv[6] + vv[7]));
        }
        sout[(size_t)r * HID + lane] =
            (1.f - ALPHA) * dinv[r] * agg + ALPHA * x0[(size_t)r * HID + lane];
    }
}

// h = (1-beta)*s + beta*(s@cw) as LDS-tiled GEMM (no broadcast VMEM reads);
// per-channel sum/sumsq via LDS matrix reduction.
__global__ __launch_bounds__(256, 3) void dense_stats_kernel(float* __restrict__ s_in,
        const float* __restrict__ cw, float* __restrict__ stats, float beta, int n) {
    __shared__ float At[64][68];   // s^T tile: At[k][r]
    __shared__ float Bt[64][68];   // cw:       Bt[k][c]
    __shared__ float redS[16][64];
    __shared__ float redQ[16][64];
    int t = threadIdx.x;
    int base = blockIdx.x * 64;
    int tx = t & 15, ty = t >> 4;
    int r0 = ty * 4, c0 = tx * 4;
#pragma unroll
    for (int i = 0; i < 4; ++i) {               // stage cw (64x64)
        int idx = (i * 256 + t) * 4;
        int k = idx >> 6, c = idx & 63;
        float4 v = *(const float4*)(cw + (size_t)k * HID + c);
        Bt[k][c] = v.x; Bt[k][c + 1] = v.y; Bt[k][c + 2] = v.z; Bt[k][c + 3] = v.w;
    }
#pragma unroll
    for (int i = 0; i < 4; ++i) {               // stage s tile transposed
        int idx = (i * 256 + t) * 4;
        int r = idx >> 6, kk = idx & 63;
        int rr = base + r; if (rr >= n) rr = n - 1;
        float4 v = *(const float4*)(s_in + (size_t)rr * HID + kk);
        At[kk][r] = v.x; At[kk + 1][r] = v.y; At[kk + 2][r] = v.z; At[kk + 3][r] = v.w;
    }
    __syncthreads();
    float acc[4][4] = {{0.f}};
#pragma unroll 4
    for (int k = 0; k < 64; ++k) {
        float4 a = *(const float4*)&At[k][r0];
        float4 b = *(const float4*)&Bt[k][c0];
        acc[0][0] += a.x * b.x; acc[0][1] += a.x * b.y; acc[0][2] += a.x * b.z; acc[0][3] += a.x * b.w;
        acc[1][0] += a.y * b.x; acc[1][1] += a.y * b.y; acc[1][2] += a.y * b.z; acc[1][3] += a.y * b.w;
        acc[2][0] += a.z * b.x; acc[2][1] += a.z * b.y; acc[2][2] += a.z * b.z; acc[2][3] += a.z * b.w;
        acc[3][0] += a.w * b.x; acc[3][1] += a.w * b.y; acc[3][2] += a.w * b.z; acc[3][3] += a.w * b.w;
    }
    float lsum[4] = {0.f, 0.f, 0.f, 0.f}, lsq[4] = {0.f, 0.f, 0.f, 0.f};
    float ob = 1.f - beta;
#pragma unroll
    for (int i = 0; i < 4; ++i) {
        int r = base + r0 + i;
        if (r < n) {
            float h0 = ob * At[c0][r0 + i]     + beta * acc[i][0];
            float h1 = ob * At[c0 + 1][r0 + i] + beta * acc[i][1];
            float h2 = ob * At[c0 + 2][r0 + i] + beta * acc[i][2];
            float h3 = ob * At[c0 + 3][r0 + i] + beta * acc[i][3];
            *(float4*)(s_in + (size_t)r * HID + c0) = make_float4(h0, h1, h2, h3);
            lsum[0] += h0; lsq[0] += h0 * h0;
            lsum[1] += h1; lsq[1] += h1 * h1;
            lsum[2] += h2; lsq[2] += h2 * h2;
            lsum[3] += h3; lsq[3] += h3 * h3;
        }
    }
    __syncthreads();   // done reading At before redS/redQ reuse timing (distinct arrays, but order writes)
#pragma unroll
    for (int j = 0; j < 4; ++j) {
        redS[ty][c0 + j] = lsum[j];
        redQ[ty][c0 + j] = lsq[j];
    }
    __syncthreads();
    if (t < 64) {
        float s = 0.f, q = 0.f;
#pragma unroll
        for (int j = 0; j < 16; ++j) { s += redS[j][t]; q += redQ[j][t]; }
        atomicAdd(&stats[t], s);
        atomicAdd(&stats[64 + t], q);
    }
}

// BN + residual + relu in place; also writes next-layer gather twin
__global__ void layerB_kernel(float4* __restrict__ h, const float4* __restrict__ xprev,
        const float* __restrict__ stats, const float* __restrict__ gamma,
        const float* __restrict__ bnb, const float* __restrict__ dinv,
        ushort4* __restrict__ g, int total4) {
    int i = blockIdx.x * blockDim.x + threadIdx.x;
    if (i >= total4) return;
    int fb = (i & 15) * 4;
    int row = i >> 4;
    float dr = dinv[row];
    float4 hv = h[i];
    float4 xp = xprev[i];
    float o[4];
    float hin[4] = { hv.x, hv.y, hv.z, hv.w };
    float xin[4] = { xp.x, xp.y, xp.z, xp.w };
#pragma unroll
    for (int j = 0; j < 4; ++j) {
        int f = fb + j;
        float mu = stats[f] * (1.0f / N_NODES);
        float var = stats[64 + f] * (1.0f / N_NODES) - mu * mu;
        if (var < 0.f) var = 0.f;
        float inv = rsqrtf(var + BN_EPS);
        float v = (hin[j] - mu) * inv * gamma[f] + bnb[f] + xin[j];
        o[j] = v > 0.f ? v : 0.f;
    }
    h[i] = make_float4(o[0], o[1], o[2], o[3]);
    ushort4 gu;
    gu.x = f2b(dr * o[0]); gu.y = f2b(dr * o[1]);
    gu.z = f2b(dr * o[2]); gu.w = f2b(dr * o[3]);
    g[i] = gu;
}

// out = x @ W1 + b1; broadcast via uniform float4 reads
__global__ __launch_bounds__(256, 2) void final_kernel(const float* __restrict__ xcur,
        const float* __restrict__ W1, const float* __restrict__ b1,
        float* __restrict__ out, int n) {
    int wave = threadIdx.x >> 6, lane = threadIdx.x & 63;
    float w[HID];
#pragma unroll
    for (int k = 0; k < HID; ++k) w[k] = W1[k * OUT_F + lane];
    float bias = b1[lane];
    int nw = gridDim.x * 4;
    for (int r = blockIdx.x * 4 + wave; r < n; r += nw) {
        const float4* xr = (const float4*)(xcur + (size_t)r * HID);
        float a0 = bias, a1 = 0.f, a2 = 0.f, a3 = 0.f;
#pragma unroll
        for (int kk = 0; kk < 16; ++kk) {
            float4 c = xr[kk];
            a0 += c.x * w[4 * kk];
            a1 += c.y * w[4 * kk + 1];
            a2 += c.z * w[4 * kk + 2];
            a3 += c.w * w[4 * kk + 3];
        }
        out[(size_t)r * OUT_F + lane] = (a0 + a1) + (a2 + a3);
    }
}

extern "C" void kernel_launch(void* const* d_in, const int* in_sizes, int n_in,
                              void* d_out, int out_size, void* d_ws, size_t ws_size,
                              hipStream_t stream) {
    const float* x     = (const float*)d_in[0];
    const int*   edges = (const int*)d_in[1];
    const float* W0    = (const float*)d_in[2];
    const float* b0    = (const float*)d_in[3];
    const float* cw    = (const float*)d_in[4];
    const float* gamma = (const float*)d_in[5];
    const float* bnb   = (const float*)d_in[6];
    const float* W1    = (const float*)d_in[7];
    const float* b1    = (const float*)d_in[8];
    float* out = (float*)d_out;

    char* ws = (char*)d_ws;
    float* x0    = (float*)(ws + OFF_X0);
    float* bufA  = (float*)(ws + OFF_HA);
    float* bufB  = (float*)(ws + OFF_HB);
    unsigned short* gbuf = (unsigned short*)(ws + OFF_GB);
    int*   scol  = (int*)(ws + OFF_SORTED);
    int*   cnt   = (int*)(ws + OFF_CNT);
    float* stats = (float*)(ws + OFF_STATS);
    float* dinv  = (float*)(ws + OFF_DINV);
    int*   rs    = (int*)(ws + OFF_ROWSTART);
    int*   cur   = (int*)(ws + OFF_CURSOR);
    int*   bsum  = (int*)(ws + OFF_BSUM);
    int2*  temp  = (int2*)(ws + OFF_HA);    // bufA reused pre-spmm
    int*   bcur  = cnt;                     // cnt reused post-scan

    hipMemsetAsync(ws + ZERO_OFF, 0, ZERO_BYTES, stream);
    hist_kernel<<<(N_EDGES + 255) / 256, 256, 0, stream>>>(edges, cnt, N_EDGES);
    dinv_kernel<<<(N_NODES + 255) / 256, 256, 0, stream>>>(cnt, dinv, N_NODES);
    blocksum_kernel<<<NSCAN_BLOCKS, SCAN_BLK, 0, stream>>>(cnt, bsum, N_NODES);
    scan_bsum_kernel<<<1, 512, 0, stream>>>(bsum, NSCAN_BLOCKS);
    scan_write_kernel<<<NSCAN_BLOCKS, SCAN_BLK, 0, stream>>>(cnt, bsum, rs, cur, N_NODES);
    bcur_init_kernel<<<(NBUCK + 255) / 256, 256, 0, stream>>>(rs, bcur, NBUCK);
    partition_kernel<<<(N_EDGES + 255) / 256, 256, 0, stream>>>(edges, bcur, temp, N_EDGES);
    scatter2_kernel<<<(N_EDGES + 255) / 256, 256, 0, stream>>>(temp, cur, scol, N_EDGES);
    fc0_kernel<<<(N_NODES + 63) / 64, 256, 0, stream>>>(x, W0, b0, dinv, x0, gbuf, N_NODES);

    const float* xc = x0;
    float* bufs[2] = { bufA, bufB };
    for (int i = 0; i < NLAYERS; ++i) {
        float beta = logf(0.5f / (float)(i + 1) + 1.0f);
        float* hb = bufs[i & 1];
        spmm_kernel<<<2048, 256, 0, stream>>>(gbuf, x0, dinv, rs, scol, hb, N_NODES);
        dense_stats_kernel<<<(N_NODES + 63) / 64, 256, 0, stream>>>(hb,
                cw + (size_t)i * HID * HID, stats + i * 128, beta, N_NODES);
        layerB_kernel<<<(N_NODES * HID / 4 + 255) / 256, 256, 0, stream>>>(
                (float4*)hb, (const float4*)xc,
                stats + i * 128, gamma + i * HID, bnb + i * HID, dinv,
                (ushort4*)gbuf, N_NODES * HID / 4);
        xc = hb;
    }
    final_kernel<<<2048, 256, 0, stream>>>(xc, W1, b1, out, N_NODES);
}

// Round 11
// 673.227 us; speedup vs baseline: 1.3361x; 1.3361x over previous
//
#include <hip/hip_runtime.h>
#include <math.h>

#define N_NODES 100000
#define N_EDGES 1000000
#define IN_F 128
#define HID 64
#define OUT_F 64
#define NLAYERS 4
#define ALPHA 0.1f
#define BN_EPS 1e-5f

#define SCAN_BLK 256
#define NSCAN_BLOCKS ((N_NODES + SCAN_BLK - 1) / SCAN_BLK)   // 391

// ---- workspace layout (bytes) ----
static const size_t OFF_X0       = 0;                       // N*64*4 = 25600000
static const size_t OFF_HA       = 25600000;
static const size_t OFF_HB       = 51200000;
static const size_t OFF_GB       = 76800000;                // N*64*2 = 12800000 (bf16, dinv-prescaled)
static const size_t OFF_SORTED   = 89600000;                // E*4 = 4000000
static const size_t OFF_CNT      = 93600000;                // N*4
static const size_t OFF_STATS    = 94000000;                // 512*4 = 2048
static const size_t OFF_DINV     = 94002048;                // N*4
static const size_t OFF_ROWSTART = 94402048;                // (N+1)*4 -> 400016
static const size_t OFF_CURSOR   = 94802064;                // N*4
static const size_t OFF_BSUM     = 95202064;                // 391*4 -> pad 2048; end = 95204112
static const size_t ZERO_OFF     = OFF_CNT;
static const size_t ZERO_BYTES   = 402048;

__device__ __forceinline__ unsigned short f2b(float f) {
    unsigned int u = __float_as_uint(f);
    u += 0x7FFFu + ((u >> 16) & 1u);        // round-to-nearest-even
    return (unsigned short)(u >> 16);
}
__device__ __forceinline__ float b2f(unsigned short h) {
    return __uint_as_float(((unsigned int)h) << 16);
}

__global__ void hist_kernel(const int* __restrict__ row, int* __restrict__ cnt, int e) {
    int i = blockIdx.x * blockDim.x + threadIdx.x;
    if (i < e) atomicAdd(&cnt[row[i]], 1);
}

__global__ void dinv_kernel(const int* __restrict__ cnt, float* __restrict__ dinv, int n) {
    int i = blockIdx.x * blockDim.x + threadIdx.x;
    if (i < n) {
        int d = cnt[i];
        dinv[i] = d > 0 ? rsqrtf((float)d) : 0.0f;
    }
}

// ---- 3-phase multi-block exclusive scan of cnt -> rs[0..n], cur ----
__global__ __launch_bounds__(SCAN_BLK) void blocksum_kernel(const int* __restrict__ cnt,
        int* __restrict__ bsum, int n) {
    __shared__ int red[SCAN_BLK / 64];
    int i = blockIdx.x * SCAN_BLK + threadIdx.x;
    int v = (i < n) ? cnt[i] : 0;
#pragma unroll
    for (int off = 32; off > 0; off >>= 1) v += __shfl_down(v, off, 64);
    if ((threadIdx.x & 63) == 0) red[threadIdx.x >> 6] = v;
    __syncthreads();
    if (threadIdx.x == 0) {
        int s = 0;
#pragma unroll
        for (int j = 0; j < SCAN_BLK / 64; ++j) s += red[j];
        bsum[blockIdx.x] = s;
    }
}

__global__ __launch_bounds__(512) void scan_bsum_kernel(int* __restrict__ bsum, int nb) {
    __shared__ int lds[512];
    int t = threadIdx.x;
    lds[t] = (t < nb) ? bsum[t] : 0;
    __syncthreads();
    for (int off = 1; off < 512; off <<= 1) {
        int v = lds[t];
        int add = (t >= off) ? lds[t - off] : 0;
        __syncthreads();
        lds[t] = v + add;
        __syncthreads();
    }
    if (t < nb) bsum[t] = (t == 0) ? 0 : lds[t - 1];
}

__global__ __launch_bounds__(SCAN_BLK) void scan_write_kernel(const int* __restrict__ cnt,
        const int* __restrict__ bsum, int* __restrict__ rs, int* __restrict__ cur, int n) {
    __shared__ int lds[SCAN_BLK];
    int t = threadIdx.x;
    int i = blockIdx.x * SCAN_BLK + t;
    int c = (i < n) ? cnt[i] : 0;
    lds[t] = c;
    __syncthreads();
    for (int off = 1; off < SCAN_BLK; off <<= 1) {
        int v = lds[t];
        int add = (t >= off) ? lds[t - off] : 0;
        __syncthreads();
        lds[t] = v + add;
        __syncthreads();
    }
    if (i < n) {
        int excl = bsum[blockIdx.x] + lds[t] - c;
        rs[i] = excl;
        cur[i] = excl;
        if (i == n - 1) rs[n] = excl + c;
    }
}

// single-pass CSR scatter (R8 version): 100k cursors -> low atomic contention;
// 70MB write-amp is bandwidth (cheap), bucket contention was latency (expensive).
__global__ void scatter_kernel(const int* __restrict__ edges, int* __restrict__ cur,
                               int* __restrict__ scol, int e) {
    int i = blockIdx.x * blockDim.x + threadIdx.x;
    if (i < e) {
        int r = edges[i];
        int c = edges[e + i];
        int pos = atomicAdd(&cur[r], 1);
        scol[pos] = c;
    }
}

// fc0 as classic LDS-tiled fp32 GEMM: [N,128]@[128,64] + bias, relu, bf16 twin.
__global__ __launch_bounds__(256, 4) void fc0_kernel(const float* __restrict__ x,
        const float* __restrict__ W0, const float* __restrict__ b0,
        const float* __restrict__ dinv, float* __restrict__ out,
        unsigned short* __restrict__ g, int n) {
    __shared__ float At[64][68];   // x^T slice: At[k][r]
    __shared__ float Bt[64][68];   // W0 slice:  Bt[k][c]
    int t = threadIdx.x;
    int base = blockIdx.x * 64;
    int tx = t & 15, ty = t >> 4;
    int r0 = ty * 4, c0 = tx * 4;
    float acc[4][4] = {{0.f}};
    for (int kc = 0; kc < IN_F; kc += 64) {
        __syncthreads();
#pragma unroll
        for (int i = 0; i < 4; ++i) {           // stage x tile (64 rows x 64 k)
            int idx = (i * 256 + t) * 4;
            int r = idx >> 6, kk = idx & 63;
            int rr = base + r; if (rr >= n) rr = n - 1;
            float4 v = *(const float4*)(x + (size_t)rr * IN_F + kc + kk);
            At[kk][r] = v.x; At[kk + 1][r] = v.y; At[kk + 2][r] = v.z; At[kk + 3][r] = v.w;
        }
#pragma unroll
        for (int i = 0; i < 4; ++i) {           // stage W0 slice (64 k x 64 c)
            int idx = (i * 256 + t) * 4;
            int k = idx >> 6, c = idx & 63;
            float4 v = *(const float4*)(W0 + (size_t)(kc + k) * HID + c);
            Bt[k][c] = v.x; Bt[k][c + 1] = v.y; Bt[k][c + 2] = v.z; Bt[k][c + 3] = v.w;
        }
        __syncthreads();
#pragma unroll 4
        for (int k = 0; k < 64; ++k) {
            float4 a = *(const float4*)&At[k][r0];
            float4 b = *(const float4*)&Bt[k][c0];
            acc[0][0] += a.x * b.x; acc[0][1] += a.x * b.y; acc[0][2] += a.x * b.z; acc[0][3] += a.x * b.w;
            acc[1][0] += a.y * b.x; acc[1][1] += a.y * b.y; acc[1][2] += a.y * b.z; acc[1][3] += a.y * b.w;
            acc[2][0] += a.z * b.x; acc[2][1] += a.z * b.y; acc[2][2] += a.z * b.z; acc[2][3] += a.z * b.w;
            acc[3][0] += a.w * b.x; acc[3][1] += a.w * b.y; acc[3][2] += a.w * b.z; acc[3][3] += a.w * b.w;
        }
    }
    float4 bias = *(const float4*)(b0 + c0);
#pragma unroll
    for (int i = 0; i < 4; ++i) {
        int r = base + r0 + i;
        if (r < n) {
            float v0 = acc[i][0] + bias.x; v0 = v0 > 0.f ? v0 : 0.f;
            float v1 = acc[i][1] + bias.y; v1 = v1 > 0.f ? v1 : 0.f;
            float v2 = acc[i][2] + bias.z; v2 = v2 > 0.f ? v2 : 0.f;
            float v3 = acc[i][3] + bias.w; v3 = v3 > 0.f ? v3 : 0.f;
            *(float4*)(out + (size_t)r * HID + c0) = make_float4(v0, v1, v2, v3);
            float dr = dinv[r];
            ushort4 gu;
            gu.x = f2b(dr * v0); gu.y = f2b(dr * v1);
            gu.z = f2b(dr * v2); gu.w = f2b(dr * v3);
            *(ushort4*)(g + (size_t)r * HID + c0) = gu;
        }
    }
}

// SPMM from bf16 dinv-prescaled gather buffer: one 128B line per edge.
__global__ __launch_bounds__(256, 8) void spmm_kernel(const unsigned short* __restrict__ g,
        const float* __restrict__ x0, const float* __restrict__ dinv,
        const int* __restrict__ rs, const int* __restrict__ scol,
        float* __restrict__ sout, int n) {
    int wave = threadIdx.x >> 6, lane = threadIdx.x & 63;
    int nw = gridDim.x * 4;
    for (int r = blockIdx.x * 4 + wave; r < n; r += nw) {
        int e0 = rs[r], e1 = rs[r + 1];
        float agg = 0.f;
        for (int e = e0; e < e1; e += 8) {
            int cc[8];
            float vv[8];
#pragma unroll
            for (int j = 0; j < 8; ++j) {
                int ee = e + j;
                cc[j] = scol[ee < e1 ? ee : e1 - 1];
            }
#pragma unroll
            for (int j = 0; j < 8; ++j) {
                float v = b2f(g[(size_t)cc[j] * HID + lane]);
                vv[j] = (e + j < e1) ? v : 0.f;
            }
            agg += ((vv[0] + vv[1]) + (vv[2] + vv[3])) +
                   ((vv[4] + vv[5]) + (vv[6] + vv[7]));
        }
        sout[(size_t)r * HID + lane] =
            (1.f - ALPHA) * dinv[r] * agg + ALPHA * x0[(size_t)r * HID + lane];
    }
}

// h = (1-beta)*s + beta*(s@cw) as LDS-tiled GEMM; stats via LDS reduction.
__global__ __launch_bounds__(256, 3) void dense_stats_kernel(float* __restrict__ s_in,
        const float* __restrict__ cw, float* __restrict__ stats, float beta, int n) {
    __shared__ float At[64][68];   // s^T tile: At[k][r]
    __shared__ float Bt[64][68];   // cw:       Bt[k][c]
    __shared__ float redS[16][64];
    __shared__ float redQ[16][64];
    int t = threadIdx.x;
    int base = blockIdx.x * 64;
    int tx = t & 15, ty = t >> 4;
    int r0 = ty * 4, c0 = tx * 4;
#pragma unroll
    for (int i = 0; i < 4; ++i) {               // stage cw (64x64)
        int idx = (i * 256 + t) * 4;
        int k = idx >> 6, c = idx & 63;
        float4 v = *(const float4*)(cw + (size_t)k * HID + c);
        Bt[k][c] = v.x; Bt[k][c + 1] = v.y; Bt[k][c + 2] = v.z; Bt[k][c + 3] = v.w;
    }
#pragma unroll
    for (int i = 0; i < 4; ++i) {               // stage s tile transposed
        int idx = (i * 256 + t) * 4;
        int r = idx >> 6, kk = idx & 63;
        int rr = base + r; if (rr >= n) rr = n - 1;
        float4 v = *(const float4*)(s_in + (size_t)rr * HID + kk);
        At[kk][r] = v.x; At[kk + 1][r] = v.y; At[kk + 2][r] = v.z; At[kk + 3][r] = v.w;
    }
    __syncthreads();
    float acc[4][4] = {{0.f}};
#pragma unroll 4
    for (int k = 0; k < 64; ++k) {
        float4 a = *(const float4*)&At[k][r0];
        float4 b = *(const float4*)&Bt[k][c0];
        acc[0][0] += a.x * b.x; acc[0][1] += a.x * b.y; acc[0][2] += a.x * b.z; acc[0][3] += a.x * b.w;
        acc[1][0] += a.y * b.x; acc[1][1] += a.y * b.y; acc[1][2] += a.y * b.z; acc[1][3] += a.y * b.w;
        acc[2][0] += a.z * b.x; acc[2][1] += a.z * b.y; acc[2][2] += a.z * b.z; acc[2][3] += a.z * b.w;
        acc[3][0] += a.w * b.x; acc[3][1] += a.w * b.y; acc[3][2] += a.w * b.z; acc[3][3] += a.w * b.w;
    }
    float lsum[4] = {0.f, 0.f, 0.f, 0.f}, lsq[4] = {0.f, 0.f, 0.f, 0.f};
    float ob = 1.f - beta;
#pragma unroll
    for (int i = 0; i < 4; ++i) {
        int r = base + r0 + i;
        if (r < n) {
            float h0 = ob * At[c0][r0 + i]     + beta * acc[i][0];
            float h1 = ob * At[c0 + 1][r0 + i] + beta * acc[i][1];
            float h2 = ob * At[c0 + 2][r0 + i] + beta * acc[i][2];
            float h3 = ob * At[c0 + 3][r0 + i] + beta * acc[i][3];
            *(float4*)(s_in + (size_t)r * HID + c0) = make_float4(h0, h1, h2, h3);
            lsum[0] += h0; lsq[0] += h0 * h0;
            lsum[1] += h1; lsq[1] += h1 * h1;
            lsum[2] += h2; lsq[2] += h2 * h2;
            lsum[3] += h3; lsq[3] += h3 * h3;
        }
    }
    __syncthreads();
#pragma unroll
    for (int j = 0; j < 4; ++j) {
        redS[ty][c0 + j] = lsum[j];
        redQ[ty][c0 + j] = lsq[j];
    }
    __syncthreads();
    if (t < 64) {
        float s = 0.f, q = 0.f;
#pragma unroll
        for (int j = 0; j < 16; ++j) { s += redS[j][t]; q += redQ[j][t]; }
        atomicAdd(&stats[t], s);
        atomicAdd(&stats[64 + t], q);
    }
}

// BN + residual + relu in place; also writes next-layer gather twin
__global__ void layerB_kernel(float4* __restrict__ h, const float4* __restrict__ xprev,
        const float* __restrict__ stats, const float* __restrict__ gamma,
        const float* __restrict__ bnb, const float* __restrict__ dinv,
        ushort4* __restrict__ g, int total4) {
    int i = blockIdx.x * blockDim.x + threadIdx.x;
    if (i >= total4) return;
    int fb = (i & 15) * 4;
    int row = i >> 4;
    float dr = dinv[row];
    float4 hv = h[i];
    float4 xp = xprev[i];
    float o[4];
    float hin[4] = { hv.x, hv.y, hv.z, hv.w };
    float xin[4] = { xp.x, xp.y, xp.z, xp.w };
#pragma unroll
    for (int j = 0; j < 4; ++j) {
        int f = fb + j;
        float mu = stats[f] * (1.0f / N_NODES);
        float var = stats[64 + f] * (1.0f / N_NODES) - mu * mu;
        if (var < 0.f) var = 0.f;
        float inv = rsqrtf(var + BN_EPS);
        float v = (hin[j] - mu) * inv * gamma[f] + bnb[f] + xin[j];
        o[j] = v > 0.f ? v : 0.f;
    }
    h[i] = make_float4(o[0], o[1], o[2], o[3]);
    ushort4 gu;
    gu.x = f2b(dr * o[0]); gu.y = f2b(dr * o[1]);
    gu.z = f2b(dr * o[2]); gu.w = f2b(dr * o[3]);
    g[i] = gu;
}

// out = x @ W1 + b1 as LDS-tiled GEMM (K=64, single chunk) + bias epilogue.
__global__ __launch_bounds__(256, 4) void final_kernel(const float* __restrict__ xcur,
        const float* __restrict__ W1, const float* __restrict__ b1,
        float* __restrict__ out, int n) {
    __shared__ float At[64][68];   // x^T tile: At[k][r]
    __shared__ float Bt[64][68];   // W1:       Bt[k][c]
    int t = threadIdx.x;
    int base = blockIdx.x * 64;
    int tx = t & 15, ty = t >> 4;
    int r0 = ty * 4, c0 = tx * 4;
#pragma unroll
    for (int i = 0; i < 4; ++i) {               // stage W1 (64x64)
        int idx = (i * 256 + t) * 4;
        int k = idx >> 6, c = idx & 63;
        float4 v = *(const float4*)(W1 + (size_t)k * OUT_F + c);
        Bt[k][c] = v.x; Bt[k][c + 1] = v.y; Bt[k][c + 2] = v.z; Bt[k][c + 3] = v.w;
    }
#pragma unroll
    for (int i = 0; i < 4; ++i) {               // stage x tile transposed
        int idx = (i * 256 + t) * 4;
        int r = idx >> 6, kk = idx & 63;
        int rr = base + r; if (rr >= n) rr = n - 1;
        float4 v = *(const float4*)(xcur + (size_t)rr * HID + kk);
        At[kk][r] = v.x; At[kk + 1][r] = v.y; At[kk + 2][r] = v.z; At[kk + 3][r] = v.w;
    }
    __syncthreads();
    float acc[4][4] = {{0.f}};
#pragma unroll 4
    for (int k = 0; k < 64; ++k) {
        float4 a = *(const float4*)&At[k][r0];
        float4 b = *(const float4*)&Bt[k][c0];
        acc[0][0] += a.x * b.x; acc[0][1] += a.x * b.y; acc[0][2] += a.x * b.z; acc[0][3] += a.x * b.w;
        acc[1][0] += a.y * b.x; acc[1][1] += a.y * b.y; acc[1][2] += a.y * b.z; acc[1][3] += a.y * b.w;
        acc[2][0] += a.z * b.x; acc[2][1] += a.z * b.y; acc[2][2] += a.z * b.z; acc[2][3] += a.z * b.w;
        acc[3][0] += a.w * b.x; acc[3][1] += a.w * b.y; acc[3][2] += a.w * b.z; acc[3][3] += a.w * b.w;
    }
    float4 bias = *(const float4*)(b1 + c0);
#pragma unroll
    for (int i = 0; i < 4; ++i) {
        int r = base + r0 + i;
        if (r < n) {
            *(float4*)(out + (size_t)r * OUT_F + c0) = make_float4(
                acc[i][0] + bias.x, acc[i][1] + bias.y,
                acc[i][2] + bias.z, acc[i][3] + bias.w);
        }
    }
}

extern "C" void kernel_launch(void* const* d_in, const int* in_sizes, int n_in,
                              void* d_out, int out_size, void* d_ws, size_t ws_size,
                              hipStream_t stream) {
    const float* x     = (const float*)d_in[0];
    const int*   edges = (const int*)d_in[1];
    const float* W0    = (const float*)d_in[2];
    const float* b0    = (const float*)d_in[3];
    const float* cw    = (const float*)d_in[4];
    const float* gamma = (const float*)d_in[5];
    const float* bnb   = (const float*)d_in[6];
    const float* W1    = (const float*)d_in[7];
    const float* b1    = (const float*)d_in[8];
    float* out = (float*)d_out;

    char* ws = (char*)d_ws;
    float* x0    = (float*)(ws + OFF_X0);
    float* bufA  = (float*)(ws + OFF_HA);
    float* bufB  = (float*)(ws + OFF_HB);
    unsigned short* gbuf = (unsigned short*)(ws + OFF_GB);
    int*   scol  = (int*)(ws + OFF_SORTED);
    int*   cnt   = (int*)(ws + OFF_CNT);
    float* stats = (float*)(ws + OFF_STATS);
    float* dinv  = (float*)(ws + OFF_DINV);
    int*   rs    = (int*)(ws + OFF_ROWSTART);
    int*   cur   = (int*)(ws + OFF_CURSOR);
    int*   bsum  = (int*)(ws + OFF_BSUM);

    hipMemsetAsync(ws + ZERO_OFF, 0, ZERO_BYTES, stream);
    hist_kernel<<<(N_EDGES + 255) / 256, 256, 0, stream>>>(edges, cnt, N_EDGES);
    dinv_kernel<<<(N_NODES + 255) / 256, 256, 0, stream>>>(cnt, dinv, N_NODES);
    blocksum_kernel<<<NSCAN_BLOCKS, SCAN_BLK, 0, stream>>>(cnt, bsum, N_NODES);
    scan_bsum_kernel<<<1, 512, 0, stream>>>(bsum, NSCAN_BLOCKS);
    scan_write_kernel<<<NSCAN_BLOCKS, SCAN_BLK, 0, stream>>>(cnt, bsum, rs, cur, N_NODES);
    scatter_kernel<<<(N_EDGES + 255) / 256, 256, 0, stream>>>(edges, cur, scol, N_EDGES);
    fc0_kernel<<<(N_NODES + 63) / 64, 256, 0, stream>>>(x, W0, b0, dinv, x0, gbuf, N_NODES);

    const float* xc = x0;
    float* bufs[2] = { bufA, bufB };
    for (int i = 0; i < NLAYERS; ++i) {
        float beta = logf(0.5f / (float)(i + 1) + 1.0f);
        float* hb = bufs[i & 1];
        spmm_kernel<<<2048, 256, 0, stream>>>(gbuf, x0, dinv, rs, scol, hb, N_NODES);
        dense_stats_kernel<<<(N_NODES + 63) / 64, 256, 0, stream>>>(hb,
                cw + (size_t)i * HID * HID, stats + i * 128, beta, N_NODES);
        layerB_kernel<<<(N_NODES * HID / 4 + 255) / 256, 256, 0, stream>>>(
                (float4*)hb, (const float4*)xc,
                stats + i * 128, gamma + i * HID, bnb + i * HID, dinv,
                (ushort4*)gbuf, N_NODES * HID / 4);
        xc = hb;
    }
    final_kernel<<<(N_NODES + 63) / 64, 256, 0, stream>>>(xc, W1, b1, out, N_NODES);
}